// Round 2
// baseline (682.392 us; speedup 1.0000x reference)
//
#include <hip/hip_runtime.h>
#include <math.h>

#define BATCH 256
#define TX 512
#define TS 512
#define EH 3
#define DH 128

__device__ __forceinline__ float sigf(float x) {
    // 1/(1+exp(-x)); robust at +-inf
    return __builtin_amdgcn_rcpf(1.0f + __expf(-x));
}
__device__ __forceinline__ float tanhfast(float x) {
    // tanh(x) = 1 - 2/(exp(2x)+1); robust at +-inf
    return fmaf(-2.0f, __builtin_amdgcn_rcpf(__expf(2.0f * x) + 1.0f), 1.0f);
}

// ---------------- encoder: LSTM H=3 over x[B,512,8], 4 lanes per batch elem ----
__global__ __launch_bounds__(64) void enc_kernel(
    const float* __restrict__ x, const float* __restrict__ h0, const float* __restrict__ c0,
    const float* __restrict__ We_ih, const float* __restrict__ We_hh,
    const float* __restrict__ be_ih, const float* __restrict__ be_hh,
    const float* __restrict__ Wfc_e, const float* __restrict__ bfc_e,
    float* __restrict__ out_z)
{
    const int gt = blockIdx.x * 64 + threadIdx.x;   // 0..1023
    const int b  = gt >> 2;                          // batch elem
    const int k  = gt & 3;                           // hidden unit (3 = spare lane)
    const int kk = (k < 3) ? k : 0;                  // clamp for loads

    // weights for this hidden unit's 4 gates (i,f,g,o = rows kk, 3+kk, 6+kk, 9+kk)
    float wx[4][8], wh[4][3], bg[4];
    #pragma unroll
    for (int g = 0; g < 4; ++g) {
        const int row = g * 3 + kk;
        #pragma unroll
        for (int m = 0; m < 8; ++m) wx[g][m] = We_ih[row * 8 + m];
        #pragma unroll
        for (int n = 0; n < 3; ++n) wh[g][n] = We_hh[row * 3 + n];
        bg[g] = be_ih[row] + be_hh[row];
    }

    float h[3];
    h[0] = h0[b * 3 + 0]; h[1] = h0[b * 3 + 1]; h[2] = h0[b * 3 + 2];
    float c = c0[b * 3 + kk];

    const float* xb = x + (size_t)b * TX * 8;
    const int base = threadIdx.x & ~3;  // 4-lane group base within the wave

    for (int t = 0; t < TX; ++t) {
        const float4 x0 = *(const float4*)(xb + t * 8);
        const float4 x1 = *(const float4*)(xb + t * 8 + 4);
        float acc[4];
        #pragma unroll
        for (int g = 0; g < 4; ++g) {
            float a = bg[g];
            a = fmaf(wx[g][0], x0.x, a);
            a = fmaf(wx[g][1], x0.y, a);
            a = fmaf(wx[g][2], x0.z, a);
            a = fmaf(wx[g][3], x0.w, a);
            a = fmaf(wx[g][4], x1.x, a);
            a = fmaf(wx[g][5], x1.y, a);
            a = fmaf(wx[g][6], x1.z, a);
            a = fmaf(wx[g][7], x1.w, a);
            a = fmaf(wh[g][0], h[0], a);
            a = fmaf(wh[g][1], h[1], a);
            a = fmaf(wh[g][2], h[2], a);
            acc[g] = a;
        }
        const float ig = sigf(acc[0]);
        const float fg = sigf(acc[1]);
        const float gg = tanhfast(acc[2]);
        const float og = sigf(acc[3]);
        c = fmaf(fg, c, ig * gg);
        const float hk = og * tanhfast(c);
        // share h within the 4-lane group
        h[0] = __shfl(hk, base + 0);
        h[1] = __shfl(hk, base + 1);
        h[2] = __shfl(hk, base + 2);
    }

    if (k == 0) {
        float zz = bfc_e[0];
        zz = fmaf(h[0], Wfc_e[0], zz);
        zz = fmaf(h[1], Wfc_e[1], zz);
        zz = fmaf(h[2], Wfc_e[2], zz);
        out_z[b] = zz;
    }
}

// ---------------- traj_hat: out[b,t,:] = s[b,t,:] @ Wfc_d^T + bfc_d ------------
__global__ __launch_bounds__(256) void traj_kernel(
    const float* __restrict__ s, const float* __restrict__ Wfc_d,
    const float* __restrict__ bfc_d, float* __restrict__ out)
{
    const int idx = blockIdx.x * 256 + threadIdx.x;   // (b*TS + t), 0..131071
    const float* st = s + (size_t)idx * 6;
    const float2 s01 = *(const float2*)(st);
    const float2 s23 = *(const float2*)(st + 2);
    const float2 s45 = *(const float2*)(st + 4);
    float o0 = bfc_d[0];
    o0 = fmaf(s01.x, Wfc_d[0], o0); o0 = fmaf(s01.y, Wfc_d[1], o0);
    o0 = fmaf(s23.x, Wfc_d[2], o0); o0 = fmaf(s23.y, Wfc_d[3], o0);
    o0 = fmaf(s45.x, Wfc_d[4], o0); o0 = fmaf(s45.y, Wfc_d[5], o0);
    float o1 = bfc_d[1];
    o1 = fmaf(s01.x, Wfc_d[6],  o1); o1 = fmaf(s01.y, Wfc_d[7],  o1);
    o1 = fmaf(s23.x, Wfc_d[8],  o1); o1 = fmaf(s23.y, Wfc_d[9],  o1);
    o1 = fmaf(s45.x, Wfc_d[10], o1); o1 = fmaf(s45.y, Wfc_d[11], o1);
    *(float2*)(out + (size_t)idx * 2) = make_float2(o0, o1);
}

// ---------------- decoder: LSTM H=128 over [s | z], one WG per batch elem -----
__global__ __launch_bounds__(512, 2) void dec_kernel(
    const float* __restrict__ s, const float* __restrict__ z,
    const float* __restrict__ Wd_ih, const float* __restrict__ Wd_hh,
    const float* __restrict__ bd_ih, const float* __restrict__ bd_hh,
    float* __restrict__ out_h)
{
    __shared__ __align__(16) float h_lds[DH];
    __shared__ float gate_lds[4 * DH];

    const int b = blockIdx.x;
    const int j = threadIdx.x;   // gate row 0..511

    // x-part weights for row j; fold z*w[6] + biases into a constant
    float wxr[7];
    #pragma unroll
    for (int m = 0; m < 7; ++m) wxr[m] = Wd_ih[j * 7 + m];
    const float gb = bd_ih[j] + bd_hh[j] + z[b] * wxr[6];

    // Whh row j -> 32 float4 in registers (128 VGPRs)
    float4 w[32];
    #pragma unroll
    for (int q = 0; q < 32; ++q)
        w[q] = *(const float4*)(Wd_hh + (size_t)j * DH + q * 4);

    float c = 0.0f;
    if (j < DH) h_lds[j] = 0.0f;
    __syncthreads();

    const float* sb = s + (size_t)b * TS * 6;
    for (int t = 0; t < TS; ++t) {
        const float* st = sb + t * 6;
        const float2 s01 = *(const float2*)(st);
        const float2 s23 = *(const float2*)(st + 2);
        const float2 s45 = *(const float2*)(st + 4);

        float a0 = gb, a1 = 0.0f, a2 = 0.0f, a3 = 0.0f;
        a0 = fmaf(wxr[0], s01.x, a0);
        a1 = fmaf(wxr[1], s01.y, a1);
        a2 = fmaf(wxr[2], s23.x, a2);
        a3 = fmaf(wxr[3], s23.y, a3);
        a0 = fmaf(wxr[4], s45.x, a0);
        a1 = fmaf(wxr[5], s45.y, a1);

        const float4* h4 = (const float4*)h_lds;
        #pragma unroll
        for (int q = 0; q < 32; ++q) {
            const float4 hv = h4[q];     // broadcast LDS read
            const float4 wq = w[q];
            a0 = fmaf(wq.x, hv.x, a0);
            a1 = fmaf(wq.y, hv.y, a1);
            a2 = fmaf(wq.z, hv.z, a2);
            a3 = fmaf(wq.w, hv.w, a3);
        }
        const float acc = (a0 + a1) + (a2 + a3);

        // apply this gate's nonlinearity before sharing (spreads transcendentals)
        const bool is_g = (j >= 2 * DH) && (j < 3 * DH);   // wave-uniform
        gate_lds[j] = is_g ? tanhfast(acc) : sigf(acc);
        __syncthreads();

        if (j < DH) {
            const float ih = gate_lds[j];
            const float fh = gate_lds[DH + j];
            const float gh = gate_lds[2 * DH + j];
            const float oh = gate_lds[3 * DH + j];
            c = fmaf(fh, c, ih * gh);
            h_lds[j] = oh * tanhfast(c);
        }
        __syncthreads();
    }

    if (j < DH) out_h[(size_t)b * DH + j] = h_lds[j];
}

extern "C" void kernel_launch(void* const* d_in, const int* in_sizes, int n_in,
                              void* d_out, int out_size, void* d_ws, size_t ws_size,
                              hipStream_t stream) {
    const float* x      = (const float*)d_in[0];
    const float* s      = (const float*)d_in[1];
    const float* h0     = (const float*)d_in[2];
    const float* c0     = (const float*)d_in[3];
    const float* We_ih  = (const float*)d_in[4];
    const float* We_hh  = (const float*)d_in[5];
    const float* be_ih  = (const float*)d_in[6];
    const float* be_hh  = (const float*)d_in[7];
    const float* Wfc_e  = (const float*)d_in[8];
    const float* bfc_e  = (const float*)d_in[9];
    const float* Wd_ih  = (const float*)d_in[10];
    const float* Wd_hh  = (const float*)d_in[11];
    const float* bd_ih  = (const float*)d_in[12];
    const float* bd_hh  = (const float*)d_in[13];
    const float* Wfc_d  = (const float*)d_in[14];
    const float* bfc_d  = (const float*)d_in[15];

    float* out      = (float*)d_out;
    float* out_z    = out;                       // [256]
    float* out_traj = out + BATCH;               // [256*512*2]
    float* out_h    = out + BATCH + BATCH * TS * 2;  // [256*128]

    enc_kernel<<<16, 64, 0, stream>>>(x, h0, c0, We_ih, We_hh, be_ih, be_hh,
                                      Wfc_e, bfc_e, out_z);
    traj_kernel<<<(BATCH * TS) / 256, 256, 0, stream>>>(s, Wfc_d, bfc_d, out_traj);
    dec_kernel<<<BATCH, 512, 0, stream>>>(s, out_z, Wd_ih, Wd_hh, bd_ih, bd_hh, out_h);
}

// Round 5
// 602.639 us; speedup vs baseline: 1.1323x; 1.1323x over previous
//
#include <hip/hip_runtime.h>
#include <math.h>

#define BATCH 256
#define TX 512
#define TS 512
#define DH 128

__device__ __forceinline__ float sigf(float x) {
    // 1/(1+exp(-x)); robust at +-inf
    return __builtin_amdgcn_rcpf(1.0f + __expf(-x));
}
__device__ __forceinline__ float tanhfast(float x) {
    // tanh(x) = 1 - 2/(exp(2x)+1); robust at +-inf
    return fmaf(-2.0f, __builtin_amdgcn_rcpf(__expf(2.0f * x) + 1.0f), 1.0f);
}
// DPP cross-lane (quad_perm): VALU pipe, no LDS traffic
template<int CTRL>
__device__ __forceinline__ float dpp_f32(float x) {
    return __int_as_float(__builtin_amdgcn_update_dpp(
        0, __float_as_int(x), CTRL, 0xF, 0xF, true));
}
#define DPP_XOR1 0xB1  // quad_perm [1,0,3,2]
#define DPP_XOR2 0x4E  // quad_perm [2,3,0,1]
#define DPP_BC0  0x00  // quad_perm [0,0,0,0]
#define DPP_BC1  0x55  // quad_perm [1,1,1,1]
#define DPP_BC2  0xAA  // quad_perm [2,2,2,2]

// ---------------- encoder: LSTM H=3 over x[B,512,8], 4 lanes per batch elem ----
__global__ __launch_bounds__(64) void enc_kernel(
    const float* __restrict__ x, const float* __restrict__ h0, const float* __restrict__ c0,
    const float* __restrict__ We_ih, const float* __restrict__ We_hh,
    const float* __restrict__ be_ih, const float* __restrict__ be_hh,
    const float* __restrict__ Wfc_e, const float* __restrict__ bfc_e,
    float* __restrict__ out_z)
{
    const int gt = blockIdx.x * 64 + threadIdx.x;   // 0..1023
    const int b  = gt >> 2;                          // batch elem
    const int k  = gt & 3;                           // hidden unit (3 = spare lane)
    const int kk = (k < 3) ? k : 0;                  // clamp for loads

    // weights for this hidden unit's 4 gates (i,f,g,o = rows kk, 3+kk, 6+kk, 9+kk)
    float wx[4][8], wh[4][3], bg[4];
    #pragma unroll
    for (int g = 0; g < 4; ++g) {
        const int row = g * 3 + kk;
        #pragma unroll
        for (int m = 0; m < 8; ++m) wx[g][m] = We_ih[row * 8 + m];
        #pragma unroll
        for (int n = 0; n < 3; ++n) wh[g][n] = We_hh[row * 3 + n];
        bg[g] = be_ih[row] + be_hh[row];
    }

    float hv0 = h0[b * 3 + 0], hv1 = h0[b * 3 + 1], hv2 = h0[b * 3 + 2];
    float c = c0[b * 3 + kk];

    const float* xb = x + (size_t)b * TX * 8;
    float4 x0 = *(const float4*)(xb);
    float4 x1 = *(const float4*)(xb + 4);

    for (int t = 0; t < TX; ++t) {
        // prefetch next x (independent of the h-chain)
        const float* xn = xb + (size_t)((t + 1 < TX) ? t + 1 : t) * 8;
        const float4 n0 = *(const float4*)(xn);
        const float4 n1 = *(const float4*)(xn + 4);

        float acc[4];
        #pragma unroll
        for (int g = 0; g < 4; ++g) {
            float a = bg[g];
            a = fmaf(wx[g][0], x0.x, a);
            a = fmaf(wx[g][1], x0.y, a);
            a = fmaf(wx[g][2], x0.z, a);
            a = fmaf(wx[g][3], x0.w, a);
            a = fmaf(wx[g][4], x1.x, a);
            a = fmaf(wx[g][5], x1.y, a);
            a = fmaf(wx[g][6], x1.z, a);
            a = fmaf(wx[g][7], x1.w, a);
            a = fmaf(wh[g][0], hv0, a);
            a = fmaf(wh[g][1], hv1, a);
            a = fmaf(wh[g][2], hv2, a);
            acc[g] = a;
        }
        const float ig = sigf(acc[0]);
        const float fg = sigf(acc[1]);
        const float gg = tanhfast(acc[2]);
        const float og = sigf(acc[3]);
        c = fmaf(fg, c, ig * gg);
        const float hk = og * tanhfast(c);
        // broadcast h within the 4-lane group via DPP (VALU, low latency)
        hv0 = dpp_f32<DPP_BC0>(hk);
        hv1 = dpp_f32<DPP_BC1>(hk);
        hv2 = dpp_f32<DPP_BC2>(hk);
        x0 = n0; x1 = n1;
    }

    if (k == 0) {
        float zz = bfc_e[0];
        zz = fmaf(hv0, Wfc_e[0], zz);
        zz = fmaf(hv1, Wfc_e[1], zz);
        zz = fmaf(hv2, Wfc_e[2], zz);
        out_z[b] = zz;
    }
}

// ---------------- traj_hat: out[b,t,:] = s[b,t,:] @ Wfc_d^T + bfc_d ------------
__global__ __launch_bounds__(256) void traj_kernel(
    const float* __restrict__ s, const float* __restrict__ Wfc_d,
    const float* __restrict__ bfc_d, float* __restrict__ out)
{
    const int idx = blockIdx.x * 256 + threadIdx.x;   // (b*TS + t), 0..131071
    const float* st = s + (size_t)idx * 6;
    const float2 s01 = *(const float2*)(st);
    const float2 s23 = *(const float2*)(st + 2);
    const float2 s45 = *(const float2*)(st + 4);
    float o0 = bfc_d[0];
    o0 = fmaf(s01.x, Wfc_d[0], o0); o0 = fmaf(s01.y, Wfc_d[1], o0);
    o0 = fmaf(s23.x, Wfc_d[2], o0); o0 = fmaf(s23.y, Wfc_d[3], o0);
    o0 = fmaf(s45.x, Wfc_d[4], o0); o0 = fmaf(s45.y, Wfc_d[5], o0);
    float o1 = bfc_d[1];
    o1 = fmaf(s01.x, Wfc_d[6],  o1); o1 = fmaf(s01.y, Wfc_d[7],  o1);
    o1 = fmaf(s23.x, Wfc_d[8],  o1); o1 = fmaf(s23.y, Wfc_d[9],  o1);
    o1 = fmaf(s45.x, Wfc_d[10], o1); o1 = fmaf(s45.y, Wfc_d[11], o1);
    *(float2*)(out + (size_t)idx * 2) = make_float2(o0, o1);
}

// ---------------- decoder: LSTM H=128, 4-way K-split, DPP quad reduction ------
// thread (j = tid>>2, q = tid&3): all 4 gate rows for h-col j over k in [32q,32q+32)
__global__ __launch_bounds__(512, 1) void dec_kernel(
    const float* __restrict__ s, const float* __restrict__ z,
    const float* __restrict__ Wd_ih, const float* __restrict__ Wd_hh,
    const float* __restrict__ bd_ih, const float* __restrict__ bd_hh,
    float* __restrict__ out_h)
{
    // h double-buffered; 4 chunks of 32 floats at stride 36 (banks 0/4/8/12 -> conflict-free)
    __shared__ __align__(16) float hbuf[2][144];

    const int b   = blockIdx.x;
    const int tid = threadIdx.x;
    const int j   = tid >> 2;    // h-col 0..127
    const int q   = tid & 3;     // K-quarter

    // Whh K-slices for the 4 gates of col j: rows g*128+j, cols [32q, 32q+32)
    float4 w[4][8];
    #pragma unroll
    for (int g = 0; g < 4; ++g) {
        const float* wp = Wd_hh + (size_t)(g * DH + j) * DH + q * 32;
        #pragma unroll
        for (int cc = 0; cc < 8; ++cc) w[g][cc] = *(const float4*)(wp + cc * 4);
    }
    // x-part: lane q owns gate q's row (s-dot computed once per gate per quad)
    const float* wi = Wd_ih + (size_t)(q * DH + j) * 7;
    const float wx0 = wi[0], wx1 = wi[1], wx2 = wi[2];
    const float wx3 = wi[3], wx4 = wi[4], wx5 = wi[5];
    const float gb  = bd_ih[q * DH + j] + bd_hh[q * DH + j] + z[b] * wi[6];

    if (tid < 144) hbuf[0][tid] = 0.0f;
    float c = 0.0f;
    float hn = 0.0f;
    __syncthreads();

    const float* sb = s + (size_t)b * TS * 6;
    float2 sA = *(const float2*)(sb);
    float2 sB = *(const float2*)(sb + 2);
    float2 sC = *(const float2*)(sb + 4);

    const int rbase = q * 36;                 // this thread's K-chunk in hbuf
    const int wpos  = (j >> 5) * 36 + (j & 31);   // h[j]'s slot

    for (int t = 0; t < TS; ++t) {
        // prefetch next s (uniform address; L1-resident after first pass)
        const float* sn = sb + (size_t)((t + 1 < TS) ? t + 1 : t) * 6;
        const float2 nA = *(const float2*)(sn);
        const float2 nB = *(const float2*)(sn + 2);
        const float2 nC = *(const float2*)(sn + 4);

        // h chunk for this K-quarter: 8 x ds_read_b128, conflict-free
        const float4* hb = (const float4*)(&hbuf[t & 1][rbase]);
        float4 h[8];
        #pragma unroll
        for (int cc = 0; cc < 8; ++cc) h[cc] = hb[cc];

        // s-dot for gate q (this lane's gate)
        float sdot = gb;
        sdot = fmaf(wx0, sA.x, sdot);
        sdot = fmaf(wx1, sA.y, sdot);
        sdot = fmaf(wx2, sB.x, sdot);
        sdot = fmaf(wx3, sB.y, sdot);
        sdot = fmaf(wx4, sC.x, sdot);
        sdot = fmaf(wx5, sC.y, sdot);

        // partial dots over this K-quarter, all 4 gates; fold sdot into gate q
        float acc[4];
        #pragma unroll
        for (int g = 0; g < 4; ++g) {
            float p0 = (g == q) ? sdot : 0.0f;
            float p1 = 0.0f, p2 = 0.0f, p3 = 0.0f;
            #pragma unroll
            for (int cc = 0; cc < 8; ++cc) {
                p0 = fmaf(w[g][cc].x, h[cc].x, p0);
                p1 = fmaf(w[g][cc].y, h[cc].y, p1);
                p2 = fmaf(w[g][cc].z, h[cc].z, p2);
                p3 = fmaf(w[g][cc].w, h[cc].w, p3);
            }
            acc[g] = (p0 + p1) + (p2 + p3);
        }

        // quad butterfly: total over the 4 K-quarters (VALU DPP, no LDS)
        #pragma unroll
        for (int g = 0; g < 4; ++g) {
            float v = acc[g];
            v += dpp_f32<DPP_XOR1>(v);
            v += dpp_f32<DPP_XOR2>(v);
            acc[g] = v;
        }

        // gates (all 4 quad lanes redundantly -> no divergence in c/h chain)
        const float ig = sigf(acc[0]);
        const float fg = sigf(acc[1]);
        const float gg = tanhfast(acc[2]);
        const float og = sigf(acc[3]);
        c  = fmaf(fg, c, ig * gg);
        hn = og * tanhfast(c);

        // publish h for next step (one lane per col), single barrier per step
        if (q == 0) hbuf[(t + 1) & 1][wpos] = hn;
        __syncthreads();

        sA = nA; sB = nB; sC = nC;
    }

    if (q == 0) out_h[(size_t)b * DH + j] = hn;
}

extern "C" void kernel_launch(void* const* d_in, const int* in_sizes, int n_in,
                              void* d_out, int out_size, void* d_ws, size_t ws_size,
                              hipStream_t stream) {
    const float* x      = (const float*)d_in[0];
    const float* s      = (const float*)d_in[1];
    const float* h0     = (const float*)d_in[2];
    const float* c0     = (const float*)d_in[3];
    const float* We_ih  = (const float*)d_in[4];
    const float* We_hh  = (const float*)d_in[5];
    const float* be_ih  = (const float*)d_in[6];
    const float* be_hh  = (const float*)d_in[7];
    const float* Wfc_e  = (const float*)d_in[8];
    const float* bfc_e  = (const float*)d_in[9];
    const float* Wd_ih  = (const float*)d_in[10];
    const float* Wd_hh  = (const float*)d_in[11];
    const float* bd_ih  = (const float*)d_in[12];
    const float* bd_hh  = (const float*)d_in[13];
    const float* Wfc_d  = (const float*)d_in[14];
    const float* bfc_d  = (const float*)d_in[15];

    float* out      = (float*)d_out;
    float* out_z    = out;                           // [256]
    float* out_traj = out + BATCH;                   // [256*512*2]
    float* out_h    = out + BATCH + BATCH * TS * 2;  // [256*128]

    enc_kernel<<<16, 64, 0, stream>>>(x, h0, c0, We_ih, We_hh, be_ih, be_hh,
                                      Wfc_e, bfc_e, out_z);
    traj_kernel<<<(BATCH * TS) / 256, 256, 0, stream>>>(s, Wfc_d, bfc_d, out_traj);
    dec_kernel<<<BATCH, 512, 0, stream>>>(s, out_z, Wd_ih, Wd_hh, bd_ih, bd_hh, out_h);
}

// Round 6
// 601.107 us; speedup vs baseline: 1.1352x; 1.0025x over previous
//
#include <hip/hip_runtime.h>
#include <math.h>

#define BATCH 256
#define TX 512
#define TS 512
#define DH 128

__device__ __forceinline__ float sigf(float x) {
    // 1/(1+exp(-x)); robust at +-inf
    return __builtin_amdgcn_rcpf(1.0f + __expf(-x));
}
__device__ __forceinline__ float tanhfast(float x) {
    // tanh(x) = 1 - 2/(exp(2x)+1); robust at +-inf
    return fmaf(-2.0f, __builtin_amdgcn_rcpf(__expf(2.0f * x) + 1.0f), 1.0f);
}
// DPP cross-lane (quad_perm): VALU pipe, no LDS traffic
template<int CTRL>
__device__ __forceinline__ float dpp_f32(float x) {
    return __int_as_float(__builtin_amdgcn_update_dpp(
        0, __float_as_int(x), CTRL, 0xF, 0xF, true));
}
#define DPP_XOR1 0xB1  // quad_perm [1,0,3,2]
#define DPP_XOR2 0x4E  // quad_perm [2,3,0,1]
#define DPP_BC0  0x00  // quad_perm [0,0,0,0]
#define DPP_BC1  0x55  // quad_perm [1,1,1,1]
#define DPP_BC2  0xAA  // quad_perm [2,2,2,2]

// ---------------- encoder: LSTM H=3 over x[B,512,8], 4 lanes per batch elem ----
__global__ __launch_bounds__(64) void enc_kernel(
    const float* __restrict__ x, const float* __restrict__ h0, const float* __restrict__ c0,
    const float* __restrict__ We_ih, const float* __restrict__ We_hh,
    const float* __restrict__ be_ih, const float* __restrict__ be_hh,
    const float* __restrict__ Wfc_e, const float* __restrict__ bfc_e,
    float* __restrict__ out_z)
{
    const int gt = blockIdx.x * 64 + threadIdx.x;   // 0..1023
    const int b  = gt >> 2;                          // batch elem
    const int k  = gt & 3;                           // hidden unit (3 = spare lane)
    const int kk = (k < 3) ? k : 0;                  // clamp for loads

    // weights for this hidden unit's 4 gates (i,f,g,o = rows kk, 3+kk, 6+kk, 9+kk)
    float wx[4][8], wh[4][3], bg[4];
    #pragma unroll
    for (int g = 0; g < 4; ++g) {
        const int row = g * 3 + kk;
        #pragma unroll
        for (int m = 0; m < 8; ++m) wx[g][m] = We_ih[row * 8 + m];
        #pragma unroll
        for (int n = 0; n < 3; ++n) wh[g][n] = We_hh[row * 3 + n];
        bg[g] = be_ih[row] + be_hh[row];
    }

    float hv0 = h0[b * 3 + 0], hv1 = h0[b * 3 + 1], hv2 = h0[b * 3 + 2];
    float c = c0[b * 3 + kk];

    const float* xb = x + (size_t)b * TX * 8;
    float4 x0 = *(const float4*)(xb);
    float4 x1 = *(const float4*)(xb + 4);

    for (int t = 0; t < TX; ++t) {
        // prefetch next x (independent of the h-chain)
        const float* xn = xb + (size_t)((t + 1 < TX) ? t + 1 : t) * 8;
        const float4 n0 = *(const float4*)(xn);
        const float4 n1 = *(const float4*)(xn + 4);

        float acc[4];
        #pragma unroll
        for (int g = 0; g < 4; ++g) {
            float a = bg[g];
            a = fmaf(wx[g][0], x0.x, a);
            a = fmaf(wx[g][1], x0.y, a);
            a = fmaf(wx[g][2], x0.z, a);
            a = fmaf(wx[g][3], x0.w, a);
            a = fmaf(wx[g][4], x1.x, a);
            a = fmaf(wx[g][5], x1.y, a);
            a = fmaf(wx[g][6], x1.z, a);
            a = fmaf(wx[g][7], x1.w, a);
            a = fmaf(wh[g][0], hv0, a);
            a = fmaf(wh[g][1], hv1, a);
            a = fmaf(wh[g][2], hv2, a);
            acc[g] = a;
        }
        const float ig = sigf(acc[0]);
        const float fg = sigf(acc[1]);
        const float gg = tanhfast(acc[2]);
        const float og = sigf(acc[3]);
        c = fmaf(fg, c, ig * gg);
        const float hk = og * tanhfast(c);
        // broadcast h within the 4-lane group via DPP (VALU, low latency)
        hv0 = dpp_f32<DPP_BC0>(hk);
        hv1 = dpp_f32<DPP_BC1>(hk);
        hv2 = dpp_f32<DPP_BC2>(hk);
        x0 = n0; x1 = n1;
    }

    if (k == 0) {
        float zz = bfc_e[0];
        zz = fmaf(hv0, Wfc_e[0], zz);
        zz = fmaf(hv1, Wfc_e[1], zz);
        zz = fmaf(hv2, Wfc_e[2], zz);
        out_z[b] = zz;
    }
}

// ---------------- traj_hat: out[b,t,:] = s[b,t,:] @ Wfc_d^T + bfc_d ------------
__global__ __launch_bounds__(256) void traj_kernel(
    const float* __restrict__ s, const float* __restrict__ Wfc_d,
    const float* __restrict__ bfc_d, float* __restrict__ out)
{
    const int idx = blockIdx.x * 256 + threadIdx.x;   // (b*TS + t), 0..131071
    const float* st = s + (size_t)idx * 6;
    const float2 s01 = *(const float2*)(st);
    const float2 s23 = *(const float2*)(st + 2);
    const float2 s45 = *(const float2*)(st + 4);
    float o0 = bfc_d[0];
    o0 = fmaf(s01.x, Wfc_d[0], o0); o0 = fmaf(s01.y, Wfc_d[1], o0);
    o0 = fmaf(s23.x, Wfc_d[2], o0); o0 = fmaf(s23.y, Wfc_d[3], o0);
    o0 = fmaf(s45.x, Wfc_d[4], o0); o0 = fmaf(s45.y, Wfc_d[5], o0);
    float o1 = bfc_d[1];
    o1 = fmaf(s01.x, Wfc_d[6],  o1); o1 = fmaf(s01.y, Wfc_d[7],  o1);
    o1 = fmaf(s23.x, Wfc_d[8],  o1); o1 = fmaf(s23.y, Wfc_d[9],  o1);
    o1 = fmaf(s45.x, Wfc_d[10], o1); o1 = fmaf(s45.y, Wfc_d[11], o1);
    *(float2*)(out + (size_t)idx * 2) = make_float2(o0, o1);
}

// ---------------- decoder: LSTM H=128, 4-way K-split, DPP quad reduction ------
// thread (j = tid>>2, q = tid&3): all 4 gate rows for h-col j over k in [32q,32q+32)
// __launch_bounds__(512, 2): 8 waves/CU = 1 WG/CU -> 256-VGPR budget, keeps
// the 128-float Whh slice in registers (R5: (512,1) fell back to 128-VGPR cap
// and spilled -> WRITE_SIZE 27 MB of scratch traffic).
__global__ __launch_bounds__(512, 2) void dec_kernel(
    const float* __restrict__ s, const float* __restrict__ z,
    const float* __restrict__ Wd_ih, const float* __restrict__ Wd_hh,
    const float* __restrict__ bd_ih, const float* __restrict__ bd_hh,
    float* __restrict__ out_h)
{
    // h double-buffered; 4 chunks of 32 floats at stride 36 (banks 0/4/8/12 -> conflict-free)
    __shared__ __align__(16) float hbuf[2][144];

    const int b   = blockIdx.x;
    const int tid = threadIdx.x;
    const int j   = tid >> 2;    // h-col 0..127
    const int q   = tid & 3;     // K-quarter

    // Whh K-slices for the 4 gates of col j: rows g*128+j, cols [32q, 32q+32)
    float4 w[4][8];
    #pragma unroll
    for (int g = 0; g < 4; ++g) {
        const float* wp = Wd_hh + (size_t)(g * DH + j) * DH + q * 32;
        #pragma unroll
        for (int cc = 0; cc < 8; ++cc) w[g][cc] = *(const float4*)(wp + cc * 4);
    }
    // x-part: lane q owns gate q's row (s-dot computed once per gate per quad)
    const float* wi = Wd_ih + (size_t)(q * DH + j) * 7;
    const float wx0 = wi[0], wx1 = wi[1], wx2 = wi[2];
    const float wx3 = wi[3], wx4 = wi[4], wx5 = wi[5];
    const float gb  = bd_ih[q * DH + j] + bd_hh[q * DH + j] + z[b] * wi[6];

    if (tid < 144) hbuf[0][tid] = 0.0f;
    float c = 0.0f;
    float hn = 0.0f;
    __syncthreads();

    const float* sb = s + (size_t)b * TS * 6;
    float2 sA = *(const float2*)(sb);
    float2 sB = *(const float2*)(sb + 2);
    float2 sC = *(const float2*)(sb + 4);

    const int rbase = q * 36;                 // this thread's K-chunk in hbuf
    const int wpos  = (j >> 5) * 36 + (j & 31);   // h[j]'s slot

    for (int t = 0; t < TS; ++t) {
        // prefetch next s (uniform address; L1-resident after first pass)
        const float* sn = sb + (size_t)((t + 1 < TS) ? t + 1 : t) * 6;
        const float2 nA = *(const float2*)(sn);
        const float2 nB = *(const float2*)(sn + 2);
        const float2 nC = *(const float2*)(sn + 4);

        // h chunk for this K-quarter: 8 x ds_read_b128, conflict-free
        const float4* hb = (const float4*)(&hbuf[t & 1][rbase]);
        float4 h[8];
        #pragma unroll
        for (int cc = 0; cc < 8; ++cc) h[cc] = hb[cc];

        // s-dot for gate q (this lane's gate)
        float sdot = gb;
        sdot = fmaf(wx0, sA.x, sdot);
        sdot = fmaf(wx1, sA.y, sdot);
        sdot = fmaf(wx2, sB.x, sdot);
        sdot = fmaf(wx3, sB.y, sdot);
        sdot = fmaf(wx4, sC.x, sdot);
        sdot = fmaf(wx5, sC.y, sdot);

        // partial dots over this K-quarter, all 4 gates; fold sdot into gate q
        float acc[4];
        #pragma unroll
        for (int g = 0; g < 4; ++g) {
            float p0 = (g == q) ? sdot : 0.0f;
            float p1 = 0.0f, p2 = 0.0f, p3 = 0.0f;
            #pragma unroll
            for (int cc = 0; cc < 8; ++cc) {
                p0 = fmaf(w[g][cc].x, h[cc].x, p0);
                p1 = fmaf(w[g][cc].y, h[cc].y, p1);
                p2 = fmaf(w[g][cc].z, h[cc].z, p2);
                p3 = fmaf(w[g][cc].w, h[cc].w, p3);
            }
            acc[g] = (p0 + p1) + (p2 + p3);
        }

        // quad butterfly: total over the 4 K-quarters (VALU DPP, no LDS)
        #pragma unroll
        for (int g = 0; g < 4; ++g) {
            float v = acc[g];
            v += dpp_f32<DPP_XOR1>(v);
            v += dpp_f32<DPP_XOR2>(v);
            acc[g] = v;
        }

        // gates (all 4 quad lanes redundantly -> no divergence in c/h chain)
        const float ig = sigf(acc[0]);
        const float fg = sigf(acc[1]);
        const float gg = tanhfast(acc[2]);
        const float og = sigf(acc[3]);
        c  = fmaf(fg, c, ig * gg);
        hn = og * tanhfast(c);

        // publish h for next step (one lane per col), single barrier per step
        if (q == 0) hbuf[(t + 1) & 1][wpos] = hn;
        __syncthreads();

        sA = nA; sB = nB; sC = nC;
    }

    if (q == 0) out_h[(size_t)b * DH + j] = hn;
}

extern "C" void kernel_launch(void* const* d_in, const int* in_sizes, int n_in,
                              void* d_out, int out_size, void* d_ws, size_t ws_size,
                              hipStream_t stream) {
    const float* x      = (const float*)d_in[0];
    const float* s      = (const float*)d_in[1];
    const float* h0     = (const float*)d_in[2];
    const float* c0     = (const float*)d_in[3];
    const float* We_ih  = (const float*)d_in[4];
    const float* We_hh  = (const float*)d_in[5];
    const float* be_ih  = (const float*)d_in[6];
    const float* be_hh  = (const float*)d_in[7];
    const float* Wfc_e  = (const float*)d_in[8];
    const float* bfc_e  = (const float*)d_in[9];
    const float* Wd_ih  = (const float*)d_in[10];
    const float* Wd_hh  = (const float*)d_in[11];
    const float* bd_ih  = (const float*)d_in[12];
    const float* bd_hh  = (const float*)d_in[13];
    const float* Wfc_d  = (const float*)d_in[14];
    const float* bfc_d  = (const float*)d_in[15];

    float* out      = (float*)d_out;
    float* out_z    = out;                           // [256]
    float* out_traj = out + BATCH;                   // [256*512*2]
    float* out_h    = out + BATCH + BATCH * TS * 2;  // [256*128]

    enc_kernel<<<16, 64, 0, stream>>>(x, h0, c0, We_ih, We_hh, be_ih, be_hh,
                                      Wfc_e, bfc_e, out_z);
    traj_kernel<<<(BATCH * TS) / 256, 256, 0, stream>>>(s, Wfc_d, bfc_d, out_traj);
    dec_kernel<<<BATCH, 512, 0, stream>>>(s, out_z, Wd_ih, Wd_hh, bd_ih, bd_hh, out_h);
}